// Round 8
// baseline (338.202 us; speedup 1.0000x reference)
//
#include <hip/hip_runtime.h>

// SeedAttention: B=8, N=1024, C=1024, H=16, HD=64. All-bf16 MFMA pipeline.
// Round 8: GEMMs -> m201-style 256x256 tile, 8 waves (wave owns 128x64),
//          4 phases/K-tile split by (kk, m-half) with B-frag register reuse,
//          2-buffer half-tile LDS (128KiB), stage-next-tile at phases 0-1,
//          vmcnt(0) only at K-tile boundary, sched_barrier-pinned MFMA.

typedef __attribute__((ext_vector_type(8))) short bf16x8;
typedef __attribute__((ext_vector_type(8))) unsigned short u16x8;
typedef __attribute__((ext_vector_type(4))) float f32x4;

#define SL2E 0.18033688011112042f  // 0.125 * log2(e)

__device__ __forceinline__ unsigned short f2bf(float f) {
  unsigned int u = __builtin_bit_cast(unsigned int, f);
  return (unsigned short)((u + 0x7FFFu + ((u >> 16) & 1u)) >> 16);
}

__device__ __forceinline__ unsigned int cvt_pk_bf16(float lo, float hi) {
  unsigned int r;
  asm("v_cvt_pk_bf16_f32 %0, %1, %2" : "=v"(r) : "v"(lo), "v"(hi));
  return r;
}

template <typename T>
__device__ __forceinline__ void gll16(const T* g, void* l) {
  __builtin_amdgcn_global_load_lds(
      (__attribute__((address_space(1))) void*)(const_cast<T*>(g)),
      (__attribute__((address_space(3))) void*)l, 16, 0, 0);
}

// ---------------- fp32 -> bf16 elementwise (x) ----------------
__global__ __launch_bounds__(256) void cvt_f2b(const float* __restrict__ in,
                                               unsigned short* __restrict__ out, int n) {
  int i = (blockIdx.x * 256 + threadIdx.x) * 8;
  if (i >= n) return;
  const float4* p4 = (const float4*)(in + i);
  float4 a = p4[0], b = p4[1];
  u16x8 o;
  o[0] = f2bf(a.x); o[1] = f2bf(a.y); o[2] = f2bf(a.z); o[3] = f2bf(a.w);
  o[4] = f2bf(b.x); o[5] = f2bf(b.y); o[6] = f2bf(b.z); o[7] = f2bf(b.w);
  *(u16x8*)(out + i) = o;
}

// ---------------- fp32 [R][C] -> bf16 [C][R] transpose (weights) ----------------
__global__ __launch_bounds__(256) void transpose_f2b(const float* __restrict__ in,
                                                     unsigned short* __restrict__ out,
                                                     int R, int C) {
  __shared__ float tile[32][33];
  int c0 = blockIdx.x * 32, r0 = blockIdx.y * 32;
  int tx = threadIdx.x, ty = threadIdx.y;
#pragma unroll
  for (int j = 0; j < 32; j += 8)
    tile[ty + j][tx] = in[(size_t)(r0 + ty + j) * C + c0 + tx];
  __syncthreads();
#pragma unroll
  for (int j = 0; j < 32; j += 8)
    out[(size_t)(c0 + ty + j) * R + r0 + tx] = f2bf(tile[tx][ty + j]);
}

// ---------------- z_cls @ Wkv_cls (fp32, K-split + atomics) ----------------
__global__ __launch_bounds__(256) void kvcls_gemm(const float* __restrict__ z,
                                                  const float* __restrict__ W,
                                                  float* __restrict__ accum) {
  int cc = blockIdx.x >> 5;
  int kc = blockIdx.x & 31;
  int c = cc * 256 + threadIdx.x;
  int k0 = kc * 64;
  float acc[8] = {0, 0, 0, 0, 0, 0, 0, 0};
  const float* wp = W + (size_t)k0 * 2048 + c;
  for (int k = 0; k < 64; ++k) {
    float wv = wp[(size_t)k * 2048];
#pragma unroll
    for (int b = 0; b < 8; ++b) acc[b] += z[b * 2048 + k0 + k] * wv;
  }
#pragma unroll
  for (int b = 0; b < 8; ++b) atomicAdd(&accum[b * 2048 + c], acc[b]);
}

__global__ __launch_bounds__(256) void kvcls_scatter(const float* __restrict__ accum,
                                                     unsigned short* __restrict__ kbuf,
                                                     unsigned short* __restrict__ vbuf) {
  int i = blockIdx.x * 256 + threadIdx.x;  // 16384 = 8 * 2048
  int b = i >> 11, c = i & 2047;
  int t = c >> 10, h = (c >> 6) & 15, d = c & 63;
  int bh = b * 16 + h;
  unsigned short v = f2bf(accum[i]);
  if (t == 0) kbuf[((size_t)bh * 1088 + 0) * 64 + d] = v;
  else        vbuf[((size_t)bh * 64 + d) * 1088 + 0] = v;
}

// ============ shared 256x256 K-loop body (BK=64, 8 waves, wave=128x64) ============
// LDS: As[buf][half][128*64], Bs likewise; 128 KiB total. Phases per K-tile:
// p=(kk<<1)|mh; B-frags loaded at mh==0, reused at mh==1.
#define GEMM256_LOOP(A_, B_, m0_, n0_)                                                 \
  f32x4 acc[8][4] = {};                                                                \
  auto STAGE_A = [&](int bb, int kt) {                                                 \
    _Pragma("unroll") for (int h = 0; h < 2; ++h)                                      \
    _Pragma("unroll") for (int i = 0; i < 2; ++i) {                                    \
      int f = i * 8192 + t * 16;                                                       \
      int row = f >> 7, colb = (f & 127) ^ ((row & 7) << 4);                           \
      gll16(A_ + (size_t)(m0_ + h * 128 + row) * 1024 + kt * 64 + (colb >> 1),         \
            (char*)As[bb][h] + f);                                                     \
    }                                                                                  \
  };                                                                                   \
  auto STAGE_B = [&](int bb, int kt) {                                                 \
    _Pragma("unroll") for (int h = 0; h < 2; ++h)                                      \
    _Pragma("unroll") for (int i = 0; i < 2; ++i) {                                    \
      int f = i * 8192 + t * 16;                                                       \
      int row = f >> 7, colb = (f & 127) ^ ((row & 7) << 4);                           \
      gll16(B_ + (size_t)(n0_ + h * 128 + row) * 1024 + kt * 64 + (colb >> 1),         \
            (char*)Bs[bb][h] + f);                                                     \
    }                                                                                  \
  };                                                                                   \
  STAGE_A(0, 0); STAGE_B(0, 0);                                                        \
  STAGE_A(1, 1); STAGE_B(1, 1);                                                        \
  asm volatile("s_waitcnt vmcnt(8)" ::: "memory");                                     \
  __builtin_amdgcn_s_barrier();                                                        \
  int brow_base = (wc & 1) * 64;                                                       \
  for (int t16 = 0; t16 < 16; ++t16) {                                                 \
    int c = t16 & 1;                                                                   \
    const char* Ac = (const char*)As[c][wr];                                           \
    const char* Bc = (const char*)Bs[c][wc >> 1];                                      \
    bf16x8 bfr[4];                                                                     \
    _Pragma("unroll") for (int p = 0; p < 4; ++p) {                                    \
      int kk = p >> 1, mh = p & 1;                                                     \
      bf16x8 afr[4];                                                                   \
      if (mh == 0) {                                                                   \
        _Pragma("unroll") for (int n = 0; n < 4; ++n) {                                \
          int row = brow_base + n * 16 + q;                                            \
          bfr[n] = *(const bf16x8*)(Bc + row * 128 +                                   \
                                    ((kk * 64 + g * 16) ^ ((row & 7) << 4)));          \
        }                                                                              \
      }                                                                                \
      _Pragma("unroll") for (int mi = 0; mi < 4; ++mi) {                               \
        int row = mh * 64 + mi * 16 + q;                                               \
        afr[mi] = *(const bf16x8*)(Ac + row * 128 +                                    \
                                   ((kk * 64 + g * 16) ^ ((row & 7) << 4)));           \
      }                                                                                \
      if (p == 0 && t16 >= 1 && t16 <= 14) STAGE_A(c ^ 1, t16 + 1);                    \
      if (p == 1 && t16 >= 1 && t16 <= 14) STAGE_B(c ^ 1, t16 + 1);                    \
      __builtin_amdgcn_s_barrier();                                                    \
      __builtin_amdgcn_sched_barrier(0);                                               \
      __builtin_amdgcn_s_setprio(1);                                                   \
      _Pragma("unroll") for (int mi = 0; mi < 4; ++mi)                                 \
      _Pragma("unroll") for (int n = 0; n < 4; ++n)                                    \
        acc[mh * 4 + mi][n] =                                                          \
            __builtin_amdgcn_mfma_f32_16x16x32_bf16(afr[mi], bfr[n],                   \
                                                    acc[mh * 4 + mi][n], 0, 0, 0);     \
      __builtin_amdgcn_s_setprio(0);                                                   \
      __builtin_amdgcn_sched_barrier(0);                                               \
      if (p == 3 && t16 < 15) asm volatile("s_waitcnt vmcnt(0)" ::: "memory");         \
      __builtin_amdgcn_s_barrier();                                                    \
    }                                                                                  \
  }

// ---------------- GEMM1: x_bf[8192,1024] @ WqkvT[3072,1024]^T -> q/k/vT ----------------
__global__ __launch_bounds__(512, 2) void gemm_qkv(const unsigned short* __restrict__ A,
                                                   const unsigned short* __restrict__ Bt,
                                                   unsigned short* __restrict__ qb,
                                                   unsigned short* __restrict__ kbuf,
                                                   unsigned short* __restrict__ vbuf) {
  __shared__ __attribute__((aligned(16))) unsigned short As[2][2][128 * 64];
  __shared__ __attribute__((aligned(16))) unsigned short Bs[2][2][128 * 64];
  int t = threadIdx.x, w = t >> 6, l = t & 63;
  int g = l >> 4, q = l & 15;
  int wg = ((int)blockIdx.x & 7) * 48 + ((int)blockIdx.x >> 3);  // 384 wgs, 48/XCD
  int tm = wg / 12, tn = wg % 12;
  int m0 = tm * 256, n0 = tn * 256;
  int wr = w >> 2, wc = w & 3;  // wave owns rows wr*128.., cols wc*64..

  GEMM256_LOOP(A, Bt, m0, n0)

  // epilogue: scatter to q [bh][1024][64], k [bh][1088][64](+1), vT [bh][64][1088](+1)
  int tsel = n0 >> 10;
  int b = m0 >> 10;
  int nqb = m0 & 1023, ncb = n0 & 1023;
#pragma unroll
  for (int m = 0; m < 8; ++m)
#pragma unroll
    for (int n = 0; n < 4; ++n)
#pragma unroll
      for (int r = 0; r < 4; ++r) {
        int nq = nqb + wr * 128 + m * 16 + g * 4 + r;
        int col = ncb + wc * 64 + n * 16 + q;
        int h = col >> 6, d = col & 63;
        int bh = b * 16 + h;
        unsigned short val = f2bf(acc[m][n][r]);
        if (tsel == 0)      qb[((size_t)bh * 1024 + nq) * 64 + d] = val;
        else if (tsel == 1) kbuf[((size_t)bh * 1088 + 1 + nq) * 64 + d] = val;
        else                vbuf[((size_t)bh * 64 + d) * 1088 + 1 + nq] = val;
      }
}

// ---------------- GEMM2: attn_out[8192,1024] @ WprojT^T + bias -> fp32 ----------------
__global__ __launch_bounds__(512, 2) void gemm_proj(const unsigned short* __restrict__ A,
                                                    const unsigned short* __restrict__ Bt,
                                                    const float* __restrict__ bias,
                                                    float* __restrict__ out) {
  __shared__ __attribute__((aligned(16))) unsigned short As[2][2][128 * 64];
  __shared__ __attribute__((aligned(16))) unsigned short Bs[2][2][128 * 64];
  int t = threadIdx.x, w = t >> 6, l = t & 63;
  int g = l >> 4, q = l & 15;
  int wg = ((int)blockIdx.x & 7) * 16 + ((int)blockIdx.x >> 3);  // 128 wgs
  int tm = wg / 4, tn = wg % 4;
  int m0 = tm * 256, n0 = tn * 256;
  int wr = w >> 2, wc = w & 3;

  GEMM256_LOOP(A, Bt, m0, n0)

  float bv[4];
#pragma unroll
  for (int n = 0; n < 4; ++n) bv[n] = bias[n0 + wc * 64 + n * 16 + q];
#pragma unroll
  for (int m = 0; m < 8; ++m)
#pragma unroll
    for (int r = 0; r < 4; ++r) {
      size_t row = m0 + wr * 128 + m * 16 + g * 4 + r;
#pragma unroll
      for (int n = 0; n < 4; ++n) {
        int col = n0 + wc * 64 + n * 16 + q;
        out[row * 1024 + col] = acc[m][n][r] + bv[n];
      }
    }
}

// ---------------- Flash attention: swapped QK^T, lane-local softmax ----------------
__global__ __launch_bounds__(256) void attn_kernel(const unsigned short* __restrict__ qbuf,
                                                   const unsigned short* __restrict__ kbuf,
                                                   const unsigned short* __restrict__ vbuf,
                                                   unsigned short* __restrict__ ob) {
  __shared__ __attribute__((aligned(16))) unsigned short Ks[2][64 * 64];
  __shared__ __attribute__((aligned(16))) unsigned short Vs[2][64 * 64];
  __shared__ __attribute__((aligned(16))) unsigned short Ps[4][16 * 64];
  int t = threadIdx.x, w = t >> 6, l = t & 63;
  int g = l >> 4, q = l & 15;
  int wg = (blockIdx.x & 7) * 256 + (blockIdx.x >> 3);
  int bh = wg >> 4, qt = wg & 15;

  const unsigned short* qrow = qbuf + ((size_t)bh * 1024 + qt * 64 + w * 16 + q) * 64;
  bf16x8 qf[2];
  qf[0] = *(const bf16x8*)(qrow + g * 8);
  qf[1] = *(const bf16x8*)(qrow + 32 + g * 8);

  const unsigned short* kg = kbuf + (size_t)bh * 1088 * 64;
  const unsigned short* vg = vbuf + (size_t)bh * 64 * 1088;
  char* Pw = (char*)Ps[w];

  auto STAGE = [&](int bb, int kt) {
#pragma unroll
    for (int i = 0; i < 2; ++i) {
      int f = i * 4096 + t * 16;
      int row = f >> 7, colb = (f & 127) ^ ((row & 7) << 4);
      gll16(kg + (size_t)(kt * 64 + row) * 64 + (colb >> 1), (char*)Ks[bb] + f);
      gll16(vg + (size_t)row * 1088 + kt * 64 + (colb >> 1), (char*)Vs[bb] + f);
    }
  };

  STAGE(0, 0);
  __syncthreads();

  f32x4 o[4] = {};
  float mrun = -__builtin_inff(), lrun = 0.f;
  int swz = (q & 7) << 4;

  for (int kt = 0; kt < 17; ++kt) {
    int cur = kt & 1;
    if (kt < 16) STAGE(cur ^ 1, kt + 1);
    f32x4 s[4] = {};
#pragma unroll
    for (int kk = 0; kk < 2; ++kk) {
      bf16x8 kf[4];
#pragma unroll
      for (int n = 0; n < 4; ++n) {
        int cb = (kk * 64 + g * 16) ^ swz;
        kf[n] = *(const bf16x8*)((const char*)Ks[cur] + (n * 16 + q) * 128 + cb);
      }
      __builtin_amdgcn_s_setprio(1);
#pragma unroll
      for (int n = 0; n < 4; ++n)
        s[n] = __builtin_amdgcn_mfma_f32_16x16x32_bf16(kf[n], qf[kk], s[n], 0, 0, 0);
      __builtin_amdgcn_s_setprio(0);
    }
    if (kt == 16) {  // keys 1024..1087: only key 1024 (n0,g0,r0) valid
#pragma unroll
      for (int n = 0; n < 4; ++n)
#pragma unroll
        for (int r = 0; r < 4; ++r)
          if (n | r) s[n][r] = -__builtin_inff();
      if (g != 0) s[0][0] = -__builtin_inff();
    }
    float mx = fmaxf(fmaxf(fmaxf(s[0][0], s[0][1]), fmaxf(s[0][2], s[0][3])),
                     fmaxf(fmaxf(s[1][0], s[1][1]), fmaxf(s[1][2], s[1][3])));
    mx = fmaxf(mx, fmaxf(fmaxf(fmaxf(s[2][0], s[2][1]), fmaxf(s[2][2], s[2][3])),
                         fmaxf(fmaxf(s[3][0], s[3][1]), fmaxf(s[3][2], s[3][3]))));
    mx = fmaxf(mx, __shfl_xor(mx, 16));
    mx = fmaxf(mx, __shfl_xor(mx, 32));
    float mnew;
    if (__all(mx <= mrun + 64.f)) {  // defer-max: P bounded by e^8
      mnew = mrun;
    } else {
      mnew = fmaxf(mrun, mx);
      float fc = exp2f((mrun - mnew) * SL2E);
      mrun = mnew;
      lrun *= fc;
#pragma unroll
      for (int n = 0; n < 4; ++n) {
        o[n][0] *= fc; o[n][1] *= fc; o[n][2] *= fc; o[n][3] *= fc;
      }
    }
    float nb = mnew * SL2E;
    float rs = 0.f;
#pragma unroll
    for (int n = 0; n < 4; ++n)
#pragma unroll
      for (int r = 0; r < 4; ++r) {
        float p = exp2f(s[n][r] * SL2E - nb);
        s[n][r] = p;
        rs += p;
      }
    rs += __shfl_xor(rs, 16);
    rs += __shfl_xor(rs, 32);
    lrun += rs;
#pragma unroll
    for (int n = 0; n < 4; ++n) {
      uint2 pk;
      pk.x = cvt_pk_bf16(s[n][0], s[n][1]);
      pk.y = cvt_pk_bf16(s[n][2], s[n][3]);
      *(uint2*)(Pw + q * 128 + ((n * 32 + g * 8) ^ swz)) = pk;
    }
    asm volatile("s_waitcnt lgkmcnt(0)" ::: "memory");
#pragma unroll
    for (int kk = 0; kk < 2; ++kk) {
      bf16x8 pb = *(const bf16x8*)(Pw + q * 128 + ((kk * 64 + g * 16) ^ swz));
      bf16x8 vf[4];
#pragma unroll
      for (int n = 0; n < 4; ++n) {
        int cb = (kk * 64 + g * 16) ^ swz;
        vf[n] = *(const bf16x8*)((const char*)Vs[cur] + (n * 16 + q) * 128 + cb);
      }
      __builtin_amdgcn_s_setprio(1);
#pragma unroll
      for (int n = 0; n < 4; ++n)
        o[n] = __builtin_amdgcn_mfma_f32_16x16x32_bf16(vf[n], pb, o[n], 0, 0, 0);
      __builtin_amdgcn_s_setprio(0);
    }
    __syncthreads();
  }
  int b = bh >> 4, h = bh & 15;
  float inv = 1.0f / lrun;
  size_t rowg = (size_t)b * 1024 + qt * 64 + w * 16 + q;
#pragma unroll
  for (int n = 0; n < 4; ++n) {
    uint2 pk;
    pk.x = cvt_pk_bf16(o[n][0] * inv, o[n][1] * inv);
    pk.y = cvt_pk_bf16(o[n][2] * inv, o[n][3] * inv);
    *(uint2*)(ob + rowg * 1024 + h * 64 + n * 16 + g * 4) = pk;
  }
}

extern "C" void kernel_launch(void* const* d_in, const int* in_sizes, int n_in,
                              void* d_out, int out_size, void* d_ws, size_t ws_size,
                              hipStream_t stream) {
  const float* x       = (const float*)d_in[0];
  const float* z_cls   = (const float*)d_in[1];
  const float* Wqkv    = (const float*)d_in[2];
  const float* Wkv_cls = (const float*)d_in[3];
  const float* Wproj   = (const float*)d_in[4];
  const float* bproj   = (const float*)d_in[5];
  float* out = (float*)d_out;

  char* p = (char*)d_ws;
  unsigned short* x_bf    = (unsigned short*)p; p += (size_t)8192 * 1024 * 2;
  unsigned short* wqkv_t  = (unsigned short*)p; p += (size_t)3072 * 1024 * 2;
  unsigned short* wproj_t = (unsigned short*)p; p += (size_t)1024 * 1024 * 2;
  unsigned short* q_buf   = (unsigned short*)p; p += (size_t)128 * 1024 * 64 * 2;
  unsigned short* k_buf   = (unsigned short*)p; p += (size_t)128 * 1088 * 64 * 2;
  unsigned short* v_buf   = (unsigned short*)p; p += (size_t)128 * 64 * 1088 * 2;
  unsigned short* attn_o  = (unsigned short*)p; p += (size_t)8192 * 1024 * 2;
  float* accum            = (float*)p;          p += (size_t)8 * 2048 * 4;

  hipMemsetAsync(accum, 0, 8 * 2048 * 4, stream);
  cvt_f2b<<<4096, 256, 0, stream>>>(x, x_bf, 8388608);
  transpose_f2b<<<dim3(96, 32), dim3(32, 8), 0, stream>>>(Wqkv, wqkv_t, 1024, 3072);
  transpose_f2b<<<dim3(32, 32), dim3(32, 8), 0, stream>>>(Wproj, wproj_t, 1024, 1024);
  kvcls_gemm<<<256, 256, 0, stream>>>(z_cls, Wkv_cls, accum);
  kvcls_scatter<<<64, 256, 0, stream>>>(accum, k_buf, v_buf);
  gemm_qkv<<<384, 512, 0, stream>>>(x_bf, wqkv_t, q_buf, k_buf, v_buf);
  attn_kernel<<<2048, 256, 0, stream>>>(q_buf, k_buf, v_buf, attn_o);
  gemm_proj<<<128, 512, 0, stream>>>(attn_o, wproj_t, bproj, out);
}

// Round 10
// 316.316 us; speedup vs baseline: 1.0692x; 1.0692x over previous
//
#include <hip/hip_runtime.h>

// SeedAttention: B=8, N=1024, C=1024, H=16, HD=64. All-bf16 MFMA pipeline.
// Round 9 (resubmit): GEMMs -> guide's T3-minimum 2-phase recipe at 128x128
//          tile, 4 waves, 64KB LDS dbuf (2 blocks/CU), one barrier + vmcnt(0)
//          per K-tile. Attn unchanged.

typedef __attribute__((ext_vector_type(8))) short bf16x8;
typedef __attribute__((ext_vector_type(8))) unsigned short u16x8;
typedef __attribute__((ext_vector_type(4))) float f32x4;

#define SL2E 0.18033688011112042f  // 0.125 * log2(e)

__device__ __forceinline__ unsigned short f2bf(float f) {
  unsigned int u = __builtin_bit_cast(unsigned int, f);
  return (unsigned short)((u + 0x7FFFu + ((u >> 16) & 1u)) >> 16);
}

__device__ __forceinline__ unsigned int cvt_pk_bf16(float lo, float hi) {
  unsigned int r;
  asm("v_cvt_pk_bf16_f32 %0, %1, %2" : "=v"(r) : "v"(lo), "v"(hi));
  return r;
}

template <typename T>
__device__ __forceinline__ void gll16(const T* g, void* l) {
  __builtin_amdgcn_global_load_lds(
      (__attribute__((address_space(1))) void*)(const_cast<T*>(g)),
      (__attribute__((address_space(3))) void*)l, 16, 0, 0);
}

// ---------------- fp32 -> bf16 elementwise (x) ----------------
__global__ __launch_bounds__(256) void cvt_f2b(const float* __restrict__ in,
                                               unsigned short* __restrict__ out, int n) {
  int i = (blockIdx.x * 256 + threadIdx.x) * 8;
  if (i >= n) return;
  const float4* p4 = (const float4*)(in + i);
  float4 a = p4[0], b = p4[1];
  u16x8 o;
  o[0] = f2bf(a.x); o[1] = f2bf(a.y); o[2] = f2bf(a.z); o[3] = f2bf(a.w);
  o[4] = f2bf(b.x); o[5] = f2bf(b.y); o[6] = f2bf(b.z); o[7] = f2bf(b.w);
  *(u16x8*)(out + i) = o;
}

// ---------------- fp32 [R][C] -> bf16 [C][R] transpose (weights) ----------------
__global__ __launch_bounds__(256) void transpose_f2b(const float* __restrict__ in,
                                                     unsigned short* __restrict__ out,
                                                     int R, int C) {
  __shared__ float tile[32][33];
  int c0 = blockIdx.x * 32, r0 = blockIdx.y * 32;
  int tx = threadIdx.x, ty = threadIdx.y;
#pragma unroll
  for (int j = 0; j < 32; j += 8)
    tile[ty + j][tx] = in[(size_t)(r0 + ty + j) * C + c0 + tx];
  __syncthreads();
#pragma unroll
  for (int j = 0; j < 32; j += 8)
    out[(size_t)(c0 + ty + j) * R + r0 + tx] = f2bf(tile[tx][ty + j]);
}

// ---------------- z_cls @ Wkv_cls (fp32, K-split + atomics) ----------------
__global__ __launch_bounds__(256) void kvcls_gemm(const float* __restrict__ z,
                                                  const float* __restrict__ W,
                                                  float* __restrict__ accum) {
  int cc = blockIdx.x >> 5;
  int kc = blockIdx.x & 31;
  int c = cc * 256 + threadIdx.x;
  int k0 = kc * 64;
  float acc[8] = {0, 0, 0, 0, 0, 0, 0, 0};
  const float* wp = W + (size_t)k0 * 2048 + c;
  for (int k = 0; k < 64; ++k) {
    float wv = wp[(size_t)k * 2048];
#pragma unroll
    for (int b = 0; b < 8; ++b) acc[b] += z[b * 2048 + k0 + k] * wv;
  }
#pragma unroll
  for (int b = 0; b < 8; ++b) atomicAdd(&accum[b * 2048 + c], acc[b]);
}

__global__ __launch_bounds__(256) void kvcls_scatter(const float* __restrict__ accum,
                                                     unsigned short* __restrict__ kbuf,
                                                     unsigned short* __restrict__ vbuf) {
  int i = blockIdx.x * 256 + threadIdx.x;  // 16384 = 8 * 2048
  int b = i >> 11, c = i & 2047;
  int t = c >> 10, h = (c >> 6) & 15, d = c & 63;
  int bh = b * 16 + h;
  unsigned short v = f2bf(accum[i]);
  if (t == 0) kbuf[((size_t)bh * 1088 + 0) * 64 + d] = v;
  else        vbuf[((size_t)bh * 64 + d) * 1088 + 0] = v;
}

// ====== shared 128x128 2-phase K-loop (BK=64, 4 waves, wave=64x64, dbuf) ======
// Per K-tile: STAGE(next) -> ds_read(cur) -> 32 MFMA -> vmcnt(0) -> barrier.
#define GEMM128_LOOP(A_, B_, m0_, n0_)                                           \
  f32x4 acc[4][4] = {};                                                          \
  auto STAGE = [&](int bb, int kt) {                                             \
    _Pragma("unroll") for (int i = 0; i < 4; ++i) {                              \
      int f = i * 4096 + t * 16;                                                 \
      int row = f >> 7, colb = (f & 127) ^ ((row & 7) << 4);                     \
      gll16(A_ + (size_t)(m0_ + row) * 1024 + kt * 64 + (colb >> 1),             \
            (char*)As[bb] + f);                                                  \
    }                                                                            \
    _Pragma("unroll") for (int i = 0; i < 4; ++i) {                              \
      int f = i * 4096 + t * 16;                                                 \
      int row = f >> 7, colb = (f & 127) ^ ((row & 7) << 4);                     \
      gll16(B_ + (size_t)(n0_ + row) * 1024 + kt * 64 + (colb >> 1),             \
            (char*)Bs[bb] + f);                                                  \
    }                                                                            \
  };                                                                             \
  STAGE(0, 0);                                                                   \
  asm volatile("s_waitcnt vmcnt(0)" ::: "memory");                               \
  __builtin_amdgcn_s_barrier();                                                  \
  for (int kt = 0; kt < 16; ++kt) {                                              \
    int cur = kt & 1;                                                            \
    if (kt < 15) STAGE(cur ^ 1, kt + 1);                                         \
    const char* Ac = (const char*)As[cur];                                       \
    const char* Bc = (const char*)Bs[cur];                                       \
    _Pragma("unroll") for (int kk = 0; kk < 2; ++kk) {                           \
      bf16x8 af[4], bf[4];                                                       \
      _Pragma("unroll") for (int m = 0; m < 4; ++m) {                            \
        int row = wr * 64 + m * 16 + q;                                          \
        af[m] = *(const bf16x8*)(Ac + row * 128 +                                \
                                 ((kk * 64 + g * 16) ^ ((row & 7) << 4)));       \
      }                                                                          \
      _Pragma("unroll") for (int n = 0; n < 4; ++n) {                            \
        int row = wc * 64 + n * 16 + q;                                          \
        bf[n] = *(const bf16x8*)(Bc + row * 128 +                                \
                                 ((kk * 64 + g * 16) ^ ((row & 7) << 4)));       \
      }                                                                          \
      __builtin_amdgcn_s_setprio(1);                                             \
      _Pragma("unroll") for (int m = 0; m < 4; ++m)                              \
      _Pragma("unroll") for (int n = 0; n < 4; ++n)                              \
        acc[m][n] = __builtin_amdgcn_mfma_f32_16x16x32_bf16(af[m], bf[n],        \
                                                            acc[m][n], 0, 0, 0);\
      __builtin_amdgcn_s_setprio(0);                                             \
    }                                                                            \
    if (kt < 15) {                                                               \
      asm volatile("s_waitcnt vmcnt(0)" ::: "memory");                           \
      __builtin_amdgcn_s_barrier();                                              \
    }                                                                            \
  }

// ---------------- GEMM1: x_bf[8192,1024] @ WqkvT[3072,1024]^T -> q/k/vT ----------------
__global__ __launch_bounds__(256) void gemm_qkv(const unsigned short* __restrict__ A,
                                                const unsigned short* __restrict__ Bt,
                                                unsigned short* __restrict__ qb,
                                                unsigned short* __restrict__ kbuf,
                                                unsigned short* __restrict__ vbuf) {
  __shared__ __attribute__((aligned(16))) unsigned short As[2][128 * 64];
  __shared__ __attribute__((aligned(16))) unsigned short Bs[2][128 * 64];
  int t = threadIdx.x, w = t >> 6, l = t & 63;
  int g = l >> 4, q = l & 15;
  // 1536 wgs; 192 consecutive per XCD
  int wg = ((int)blockIdx.x & 7) * 192 + ((int)blockIdx.x >> 3);
  int tm = wg / 24, tn = wg % 24;
  int m0 = tm * 128, n0 = tn * 128;
  int wr = w >> 1, wc = w & 1;

  GEMM128_LOOP(A, Bt, m0, n0)

  // epilogue: scatter to q [bh][1024][64], k [bh][1088][64](+1), vT [bh][64][1088](+1)
  int tsel = n0 >> 10;
  int b = m0 >> 10;
  int nqb = m0 & 1023, ncb = n0 & 1023;
#pragma unroll
  for (int m = 0; m < 4; ++m)
#pragma unroll
    for (int n = 0; n < 4; ++n)
#pragma unroll
      for (int r = 0; r < 4; ++r) {
        int nq = nqb + wr * 64 + m * 16 + g * 4 + r;
        int col = ncb + wc * 64 + n * 16 + q;
        int h = col >> 6, d = col & 63;
        int bh = b * 16 + h;
        unsigned short val = f2bf(acc[m][n][r]);
        if (tsel == 0)      qb[((size_t)bh * 1024 + nq) * 64 + d] = val;
        else if (tsel == 1) kbuf[((size_t)bh * 1088 + 1 + nq) * 64 + d] = val;
        else                vbuf[((size_t)bh * 64 + d) * 1088 + 1 + nq] = val;
      }
}

// ---------------- GEMM2: attn_out[8192,1024] @ WprojT^T + bias -> fp32 ----------------
__global__ __launch_bounds__(256) void gemm_proj(const unsigned short* __restrict__ A,
                                                 const unsigned short* __restrict__ Bt,
                                                 const float* __restrict__ bias,
                                                 float* __restrict__ out) {
  __shared__ __attribute__((aligned(16))) unsigned short As[2][128 * 64];
  __shared__ __attribute__((aligned(16))) unsigned short Bs[2][128 * 64];
  int t = threadIdx.x, w = t >> 6, l = t & 63;
  int g = l >> 4, q = l & 15;
  int wg = ((int)blockIdx.x & 7) * 64 + ((int)blockIdx.x >> 3);  // 512 wgs
  int tm = wg / 8, tn = wg % 8;
  int m0 = tm * 128, n0 = tn * 128;
  int wr = w >> 1, wc = w & 1;

  GEMM128_LOOP(A, Bt, m0, n0)

  float bv[4];
#pragma unroll
  for (int n = 0; n < 4; ++n) bv[n] = bias[n0 + wc * 64 + n * 16 + q];
#pragma unroll
  for (int m = 0; m < 4; ++m)
#pragma unroll
    for (int r = 0; r < 4; ++r) {
      size_t row = m0 + wr * 64 + m * 16 + g * 4 + r;
#pragma unroll
      for (int n = 0; n < 4; ++n) {
        int col = n0 + wc * 64 + n * 16 + q;
        out[row * 1024 + col] = acc[m][n][r] + bv[n];
      }
    }
}

// ---------------- Flash attention: swapped QK^T, lane-local softmax ----------------
__global__ __launch_bounds__(256) void attn_kernel(const unsigned short* __restrict__ qbuf,
                                                   const unsigned short* __restrict__ kbuf,
                                                   const unsigned short* __restrict__ vbuf,
                                                   unsigned short* __restrict__ ob) {
  __shared__ __attribute__((aligned(16))) unsigned short Ks[2][64 * 64];
  __shared__ __attribute__((aligned(16))) unsigned short Vs[2][64 * 64];
  __shared__ __attribute__((aligned(16))) unsigned short Ps[4][16 * 64];
  int t = threadIdx.x, w = t >> 6, l = t & 63;
  int g = l >> 4, q = l & 15;
  int wg = (blockIdx.x & 7) * 256 + (blockIdx.x >> 3);
  int bh = wg >> 4, qt = wg & 15;

  const unsigned short* qrow = qbuf + ((size_t)bh * 1024 + qt * 64 + w * 16 + q) * 64;
  bf16x8 qf[2];
  qf[0] = *(const bf16x8*)(qrow + g * 8);
  qf[1] = *(const bf16x8*)(qrow + 32 + g * 8);

  const unsigned short* kg = kbuf + (size_t)bh * 1088 * 64;
  const unsigned short* vg = vbuf + (size_t)bh * 64 * 1088;
  char* Pw = (char*)Ps[w];

  auto STAGE = [&](int bb, int kt) {
#pragma unroll
    for (int i = 0; i < 2; ++i) {
      int f = i * 4096 + t * 16;
      int row = f >> 7, colb = (f & 127) ^ ((row & 7) << 4);
      gll16(kg + (size_t)(kt * 64 + row) * 64 + (colb >> 1), (char*)Ks[bb] + f);
      gll16(vg + (size_t)row * 1088 + kt * 64 + (colb >> 1), (char*)Vs[bb] + f);
    }
  };

  STAGE(0, 0);
  __syncthreads();

  f32x4 o[4] = {};
  float mrun = -__builtin_inff(), lrun = 0.f;
  int swz = (q & 7) << 4;

  for (int kt = 0; kt < 17; ++kt) {
    int cur = kt & 1;
    if (kt < 16) STAGE(cur ^ 1, kt + 1);
    f32x4 s[4] = {};
#pragma unroll
    for (int kk = 0; kk < 2; ++kk) {
      bf16x8 kf[4];
#pragma unroll
      for (int n = 0; n < 4; ++n) {
        int cb = (kk * 64 + g * 16) ^ swz;
        kf[n] = *(const bf16x8*)((const char*)Ks[cur] + (n * 16 + q) * 128 + cb);
      }
      __builtin_amdgcn_s_setprio(1);
#pragma unroll
      for (int n = 0; n < 4; ++n)
        s[n] = __builtin_amdgcn_mfma_f32_16x16x32_bf16(kf[n], qf[kk], s[n], 0, 0, 0);
      __builtin_amdgcn_s_setprio(0);
    }
    if (kt == 16) {  // keys 1024..1087: only key 1024 (n0,g0,r0) valid
#pragma unroll
      for (int n = 0; n < 4; ++n)
#pragma unroll
        for (int r = 0; r < 4; ++r)
          if (n | r) s[n][r] = -__builtin_inff();
      if (g != 0) s[0][0] = -__builtin_inff();
    }
    float mx = fmaxf(fmaxf(fmaxf(s[0][0], s[0][1]), fmaxf(s[0][2], s[0][3])),
                     fmaxf(fmaxf(s[1][0], s[1][1]), fmaxf(s[1][2], s[1][3])));
    mx = fmaxf(mx, fmaxf(fmaxf(fmaxf(s[2][0], s[2][1]), fmaxf(s[2][2], s[2][3])),
                         fmaxf(fmaxf(s[3][0], s[3][1]), fmaxf(s[3][2], s[3][3]))));
    mx = fmaxf(mx, __shfl_xor(mx, 16));
    mx = fmaxf(mx, __shfl_xor(mx, 32));
    float mnew;
    if (__all(mx <= mrun + 64.f)) {  // defer-max: P bounded by e^8
      mnew = mrun;
    } else {
      mnew = fmaxf(mrun, mx);
      float fc = exp2f((mrun - mnew) * SL2E);
      mrun = mnew;
      lrun *= fc;
#pragma unroll
      for (int n = 0; n < 4; ++n) {
        o[n][0] *= fc; o[n][1] *= fc; o[n][2] *= fc; o[n][3] *= fc;
      }
    }
    float nb = mnew * SL2E;
    float rs = 0.f;
#pragma unroll
    for (int n = 0; n < 4; ++n)
#pragma unroll
      for (int r = 0; r < 4; ++r) {
        float p = exp2f(s[n][r] * SL2E - nb);
        s[n][r] = p;
        rs += p;
      }
    rs += __shfl_xor(rs, 16);
    rs += __shfl_xor(rs, 32);
    lrun += rs;
#pragma unroll
    for (int n = 0; n < 4; ++n) {
      uint2 pk;
      pk.x = cvt_pk_bf16(s[n][0], s[n][1]);
      pk.y = cvt_pk_bf16(s[n][2], s[n][3]);
      *(uint2*)(Pw + q * 128 + ((n * 32 + g * 8) ^ swz)) = pk;
    }
    asm volatile("s_waitcnt lgkmcnt(0)" ::: "memory");
#pragma unroll
    for (int kk = 0; kk < 2; ++kk) {
      bf16x8 pb = *(const bf16x8*)(Pw + q * 128 + ((kk * 64 + g * 16) ^ swz));
      bf16x8 vf[4];
#pragma unroll
      for (int n = 0; n < 4; ++n) {
        int cb = (kk * 64 + g * 16) ^ swz;
        vf[n] = *(const bf16x8*)((const char*)Vs[cur] + (n * 16 + q) * 128 + cb);
      }
      __builtin_amdgcn_s_setprio(1);
#pragma unroll
      for (int n = 0; n < 4; ++n)
        o[n] = __builtin_amdgcn_mfma_f32_16x16x32_bf16(vf[n], pb, o[n], 0, 0, 0);
      __builtin_amdgcn_s_setprio(0);
    }
    __syncthreads();
  }
  int b = bh >> 4, h = bh & 15;
  float inv = 1.0f / lrun;
  size_t rowg = (size_t)b * 1024 + qt * 64 + w * 16 + q;
#pragma unroll
  for (int n = 0; n < 4; ++n) {
    uint2 pk;
    pk.x = cvt_pk_bf16(o[n][0] * inv, o[n][1] * inv);
    pk.y = cvt_pk_bf16(o[n][2] * inv, o[n][3] * inv);
    *(uint2*)(ob + rowg * 1024 + h * 64 + n * 16 + g * 4) = pk;
  }
}

extern "C" void kernel_launch(void* const* d_in, const int* in_sizes, int n_in,
                              void* d_out, int out_size, void* d_ws, size_t ws_size,
                              hipStream_t stream) {
  const float* x       = (const float*)d_in[0];
  const float* z_cls   = (const float*)d_in[1];
  const float* Wqkv    = (const float*)d_in[2];
  const float* Wkv_cls = (const float*)d_in[3];
  const float* Wproj   = (const float*)d_in[4];
  const float* bproj   = (const float*)d_in[5];
  float* out = (float*)d_out;

  char* p = (char*)d_ws;
  unsigned short* x_bf    = (unsigned short*)p; p += (size_t)8192 * 1024 * 2;
  unsigned short* wqkv_t  = (unsigned short*)p; p += (size_t)3072 * 1024 * 2;
  unsigned short* wproj_t = (unsigned short*)p; p += (size_t)1024 * 1024 * 2;
  unsigned short* q_buf   = (unsigned short*)p; p += (size_t)128 * 1024 * 64 * 2;
  unsigned short* k_buf   = (unsigned short*)p; p += (size_t)128 * 1088 * 64 * 2;
  unsigned short* v_buf   = (unsigned short*)p; p += (size_t)128 * 64 * 1088 * 2;
  unsigned short* attn_o  = (unsigned short*)p; p += (size_t)8192 * 1024 * 2;
  float* accum            = (float*)p;          p += (size_t)8 * 2048 * 4;

  hipMemsetAsync(accum, 0, 8 * 2048 * 4, stream);
  cvt_f2b<<<4096, 256, 0, stream>>>(x, x_bf, 8388608);
  transpose_f2b<<<dim3(96, 32), dim3(32, 8), 0, stream>>>(Wqkv, wqkv_t, 1024, 3072);
  transpose_f2b<<<dim3(32, 32), dim3(32, 8), 0, stream>>>(Wproj, wproj_t, 1024, 1024);
  kvcls_gemm<<<256, 256, 0, stream>>>(z_cls, Wkv_cls, accum);
  kvcls_scatter<<<64, 256, 0, stream>>>(accum, k_buf, v_buf);
  gemm_qkv<<<1536, 256, 0, stream>>>(x_bf, wqkv_t, q_buf, k_buf, v_buf);
  attn_kernel<<<2048, 256, 0, stream>>>(q_buf, k_buf, v_buf, attn_o);
  gemm_proj<<<512, 256, 0, stream>>>(attn_o, wproj_t, bproj, out);
}